// Round 11
// baseline (486.368 us; speedup 1.0000x reference)
//
#include <hip/hip_runtime.h>

// RoI crop_and_resize — R10 DIAGNOSTIC build.
// Exact R5 structure (best passing: 80.7us) wrapped in an in-kernel x5
// repeat so the dispatch (~400us) lands in rocprof's top-5 and we can
// finally read OUR kernel's FETCH_SIZE / WRITE_SIZE / VALUBusy.
// Deterministic: every pass computes and stores identical values.
// An asm barrier on the feature pointer prevents cross-pass load CSE so
// pass 2..5 re-issue real loads (steady-state refetch becomes visible).
//
// Decision rule: FETCH_SIZE >= ~500MB -> write-stream evicts feature slice
// from L2 (H1, attack read protection). FETCH_SIZE <= ~150MB -> reads are
// L2-served and the NT write path itself caps at ~5.5TB/s (H2, R5 is near
// the practical roofline).

#define FH 50
#define FW 50
#define FC 1024
#define PH 14
#define PW 14
#define CS 64                 // channels per slice
#define NSL (FC / CS)         // 16 slices
#define QS (CS / 4)           // 16 f32x4 quads per slice
#define REPEAT 5

typedef float f32x4 __attribute__((ext_vector_type(4)));

__global__ __launch_bounds__(256) void roi_crop_resize_kernel(
    const float* __restrict__ feat,
    const float* __restrict__ rois,
    const int* __restrict__ img_size,
    float* __restrict__ out)
{
    int bid = blockIdx.x;
    int n = bid >> 4;          // RoI index
    int s = bid & (NSL - 1);   // channel slice -> XCD s&7
    int t = threadIdx.x;
    int q = t & 15;            // quad within slice (16 x f32x4 = 64 ch)
    int j = t >> 4;            // 0..15; j<14 active for compute

    float hs = (float)img_size[0];
    float ws = (float)img_size[1];
    float by1 = rois[n * 4 + 0] / hs;
    float bx1 = rois[n * 4 + 1] / ws;
    float by2 = rois[n * 4 + 2] / hs;
    float bx2 = rois[n * 4 + 3] / ws;

    float ybase = by1 * (float)(FH - 1);
    float dy    = (by2 - by1) * (float)(FH - 1) * (1.0f / (float)(PH - 1));
    float xbase = bx1 * (float)(FW - 1);
    float dxs   = (bx2 - bx1) * (float)(FW - 1) * (1.0f / (float)(PW - 1));

    // per-lane x interpolation (clamped so inactive lanes form valid addrs)
    float xs  = xbase + (float)j * dxs;
    float x0f = floorf(xs);
    float wx  = xs - x0f;
    int x0 = (int)fminf(fmaxf(x0f,        0.0f), (float)(FW - 1));
    int x1 = (int)fminf(fmaxf(x0f + 1.0f, 0.0f), (float)(FW - 1));
    float omwx = 1.0f - wx;

    int sq = s * QS + q;                       // quad index within a pixel
    f32x4* ob = (f32x4*)out + ((size_t)n * (PH * PW)) * (FC / 4) + sq;

    bool active = (j < PW);

    const float* fbase = feat;
    #pragma unroll 1
    for (int rep = 0; rep < REPEAT; ++rep) {
        // opaque-ify the feature pointer so passes 2..5 can't CSE the loads
        asm volatile("" : "+v"(fbase));
        const f32x4* fq = (const f32x4*)fbase;

        #pragma unroll
        for (int i = 0; i < PH; ++i) {
            float ysf = ybase + (float)i * dy;
            float y0f = floorf(ysf);
            float wy  = ysf - y0f;
            int r0 = (int)fminf(fmaxf(y0f,        0.0f), (float)(FH - 1));
            int r1 = (int)fminf(fmaxf(y0f + 1.0f, 0.0f), (float)(FH - 1));
            float omwy = 1.0f - wy;

            if (active) {
                int bT = (r0 * FW) * (FC / 4) + sq;
                int bB = (r1 * FW) * (FC / 4) + sq;
                f32x4 a = fq[bT + x0 * (FC / 4)];
                f32x4 b = fq[bT + x1 * (FC / 4)];
                f32x4 c = fq[bB + x0 * (FC / 4)];
                f32x4 d = fq[bB + x1 * (FC / 4)];

                // reference ordering: top = a*(1-wx)+b*wx; bot = c*(1-wx)+d*wx;
                // out = top*(1-wy) + bot*wy
                f32x4 res = (a * omwx + b * wx) * omwy + (c * omwx + d * wx) * wy;

                __builtin_nontemporal_store(res, ob + (i * PW + j) * (FC / 4));
            }
        }
    }
}

extern "C" void kernel_launch(void* const* d_in, const int* in_sizes, int n_in,
                              void* d_out, int out_size, void* d_ws, size_t ws_size,
                              hipStream_t stream) {
    const float* feat     = (const float*)d_in[0];
    const float* rois     = (const float*)d_in[1];
    const int*   img_size = (const int*)d_in[2];
    float* out = (float*)d_out;

    int n_rois = in_sizes[1] / 4;            // 512
    int grid   = n_rois * NSL;               // 8192 blocks

    roi_crop_resize_kernel<<<grid, 256, 0, stream>>>(feat, rois, img_size, out);
}

// Round 12
// 79.521 us; speedup vs baseline: 6.1162x; 6.1162x over previous
//
#include <hip/hip_runtime.h>

// RoI crop_and_resize (tf.image.crop_and_resize, bilinear), single image.
// feature: [1,50,50,1024] f32; rois: [512,4] f32; img_size: [2] i32.
// Output: [512,14,14,1024] f32.
//
// R11: attack L2-read bandwidth (R10 diag: FETCH=5MB/5 passes -> reads are
// fully L2-served; per-XCD L2 traffic ~3.8 of ~4.3 TB/s -> L2-bound).
// Cut L2 reads by making the bilinear reuse land in L1:
//   - CS=32 channels/slice -> row-pair window ~4.9 KB/block
//   - 128-thread blocks
//   - 26 KB dummy LDS caps residency at 6 blocks/CU -> 6*4.9 ~ 29 KB <= 32KB L1
// Keeps: slice->XCD pinning (s&7; each XCD reads 4/32 slices = 1.28 MB,
// L2-resident) and CU-scope nontemporal stores (R7 showed plain stores
// evict the feature slice; R8/R9 showed system-scope NT is incoherent with
// the harness memset).

#define FH 50
#define FW 50
#define FC 1024
#define PH 14
#define PW 14
#define CS 32                 // channels per slice
#define NSL (FC / CS)         // 32 slices
#define QS (CS / 4)           // 8 f32x4 quads per slice

typedef float f32x4 __attribute__((ext_vector_type(4)));

__global__ __launch_bounds__(128) void roi_crop_resize_kernel(
    const float* __restrict__ feat,
    const float* __restrict__ rois,
    const int* __restrict__ img_size,
    float* __restrict__ out)
{
    // Occupancy governor: 26 KB LDS -> floor(160/26) = 6 blocks/CU, so the
    // six resident blocks' L1 windows (~4.9 KB each) fit the 32 KB L1.
    __shared__ float lds_cap[6656];

    int bid = blockIdx.x;
    int n = bid >> 5;          // RoI index
    int s = bid & (NSL - 1);   // channel slice -> XCD s&7
    int t = threadIdx.x;
    int q = t & 7;             // quad within slice (8 x f32x4 = 32 ch)
    int j = t >> 3;            // 0..15; j<14 active for compute

    // keep the LDS allocation alive without ever touching it
    asm volatile("" :: "v"(&lds_cap[0]));

    float hs = (float)img_size[0];
    float ws = (float)img_size[1];
    float by1 = rois[n * 4 + 0] / hs;
    float bx1 = rois[n * 4 + 1] / ws;
    float by2 = rois[n * 4 + 2] / hs;
    float bx2 = rois[n * 4 + 3] / ws;

    float ybase = by1 * (float)(FH - 1);
    float dy    = (by2 - by1) * (float)(FH - 1) * (1.0f / (float)(PH - 1));
    float xbase = bx1 * (float)(FW - 1);
    float dxs   = (bx2 - bx1) * (float)(FW - 1) * (1.0f / (float)(PW - 1));

    // per-lane x interpolation (clamped so inactive lanes form valid addrs)
    float xs  = xbase + (float)j * dxs;
    float x0f = floorf(xs);
    float wx  = xs - x0f;
    int x0 = (int)fminf(fmaxf(x0f,        0.0f), (float)(FW - 1));
    int x1 = (int)fminf(fmaxf(x0f + 1.0f, 0.0f), (float)(FW - 1));
    float omwx = 1.0f - wx;

    const f32x4* fq = (const f32x4*)feat;
    int sq = s * QS + q;                       // quad index within a pixel
    f32x4* ob = (f32x4*)out + ((size_t)n * (PH * PW)) * (FC / 4) + sq;

    bool active = (j < PW);

    #pragma unroll
    for (int i = 0; i < PH; ++i) {
        float ysf = ybase + (float)i * dy;
        float y0f = floorf(ysf);
        float wy  = ysf - y0f;
        int r0 = (int)fminf(fmaxf(y0f,        0.0f), (float)(FH - 1));
        int r1 = (int)fminf(fmaxf(y0f + 1.0f, 0.0f), (float)(FH - 1));
        float omwy = 1.0f - wy;

        if (active) {
            int bT = (r0 * FW) * (FC / 4) + sq;
            int bB = (r1 * FW) * (FC / 4) + sq;
            f32x4 a = fq[bT + x0 * (FC / 4)];
            f32x4 b = fq[bT + x1 * (FC / 4)];
            f32x4 c = fq[bB + x0 * (FC / 4)];
            f32x4 d = fq[bB + x1 * (FC / 4)];

            // reference ordering: top = a*(1-wx)+b*wx; bot = c*(1-wx)+d*wx;
            // out = top*(1-wy) + bot*wy
            f32x4 res = (a * omwx + b * wx) * omwy + (c * omwx + d * wx) * wy;

            __builtin_nontemporal_store(res, ob + (i * PW + j) * (FC / 4));
        }
    }
}

extern "C" void kernel_launch(void* const* d_in, const int* in_sizes, int n_in,
                              void* d_out, int out_size, void* d_ws, size_t ws_size,
                              hipStream_t stream) {
    const float* feat     = (const float*)d_in[0];
    const float* rois     = (const float*)d_in[1];
    const int*   img_size = (const int*)d_in[2];
    float* out = (float*)d_out;

    int n_rois = in_sizes[1] / 4;            // 512
    int grid   = n_rois * NSL;               // 16384 blocks

    roi_crop_resize_kernel<<<grid, 128, 0, stream>>>(feat, rois, img_size, out);
}

// Round 13
// 77.609 us; speedup vs baseline: 6.2669x; 1.0246x over previous
//
#include <hip/hip_runtime.h>

// RoI crop_and_resize (tf.image.crop_and_resize, bilinear), single image.
// feature: [1,50,50,1024] f32; rois: [512,4] f32; img_size: [2] i32.
// Output: [512,14,14,1024] f32.
//
// R12: CS=128 (8 slices) -> bid = 8n+s gives EXACT slice<->XCD 1:1 pinning.
// Each XCD writes one 512B contiguous chunk per 4KB cell (vs 2 disjoint
// 256B chunks in R5) -> half the DRAM row activations on the write stream;
// reads: each XCD touches exactly one slice = 50*50*128*4 = 1.28MB,
// L2-resident (same as R5). 512-thread blocks: j = t>>5 (j<14 active),
// q = t&31; a wave covers 2 j-columns x 512B bursts.
// Keeps CU-scope nontemporal stores (R7: plain stores -42%; R8/9:
// system-scope NT incoherent with harness readback).
// Exonerated by A/B so far: wave burst width (R6), plain stores (R7),
// L2-bypass (R8/9), L1 capture via occupancy cap (R11), L2 read BW (R4,R11).

#define FH 50
#define FW 50
#define FC 1024
#define PH 14
#define PW 14
#define CS 128                // channels per slice
#define NSL (FC / CS)         // 8 slices
#define QS (CS / 4)           // 32 f32x4 quads per slice

typedef float f32x4 __attribute__((ext_vector_type(4)));

__global__ __launch_bounds__(512) void roi_crop_resize_kernel(
    const float* __restrict__ feat,
    const float* __restrict__ rois,
    const int* __restrict__ img_size,
    float* __restrict__ out)
{
    int bid = blockIdx.x;
    int n = bid >> 3;          // RoI index
    int s = bid & (NSL - 1);   // channel slice == XCD (bid&7)
    int t = threadIdx.x;
    int q = t & 31;            // quad within slice (32 x f32x4 = 128 ch)
    int j = t >> 5;            // 0..15; j<14 active for compute

    float hs = (float)img_size[0];
    float ws = (float)img_size[1];
    float by1 = rois[n * 4 + 0] / hs;
    float bx1 = rois[n * 4 + 1] / ws;
    float by2 = rois[n * 4 + 2] / hs;
    float bx2 = rois[n * 4 + 3] / ws;

    float ybase = by1 * (float)(FH - 1);
    float dy    = (by2 - by1) * (float)(FH - 1) * (1.0f / (float)(PH - 1));
    float xbase = bx1 * (float)(FW - 1);
    float dxs   = (bx2 - bx1) * (float)(FW - 1) * (1.0f / (float)(PW - 1));

    // per-lane x interpolation (clamped so inactive lanes form valid addrs)
    float xs  = xbase + (float)j * dxs;
    float x0f = floorf(xs);
    float wx  = xs - x0f;
    int x0 = (int)fminf(fmaxf(x0f,        0.0f), (float)(FW - 1));
    int x1 = (int)fminf(fmaxf(x0f + 1.0f, 0.0f), (float)(FW - 1));
    float omwx = 1.0f - wx;

    const f32x4* fq = (const f32x4*)feat;
    int sq = s * QS + q;                       // quad index within a pixel
    f32x4* ob = (f32x4*)out + ((size_t)n * (PH * PW)) * (FC / 4) + sq;

    bool active = (j < PW);

    #pragma unroll
    for (int i = 0; i < PH; ++i) {
        float ysf = ybase + (float)i * dy;
        float y0f = floorf(ysf);
        float wy  = ysf - y0f;
        int r0 = (int)fminf(fmaxf(y0f,        0.0f), (float)(FH - 1));
        int r1 = (int)fminf(fmaxf(y0f + 1.0f, 0.0f), (float)(FH - 1));
        float omwy = 1.0f - wy;

        if (active) {
            int bT = (r0 * FW) * (FC / 4) + sq;
            int bB = (r1 * FW) * (FC / 4) + sq;
            f32x4 a = fq[bT + x0 * (FC / 4)];
            f32x4 b = fq[bT + x1 * (FC / 4)];
            f32x4 c = fq[bB + x0 * (FC / 4)];
            f32x4 d = fq[bB + x1 * (FC / 4)];

            // reference ordering: top = a*(1-wx)+b*wx; bot = c*(1-wx)+d*wx;
            // out = top*(1-wy) + bot*wy
            f32x4 res = (a * omwx + b * wx) * omwy + (c * omwx + d * wx) * wy;

            __builtin_nontemporal_store(res, ob + (i * PW + j) * (FC / 4));
        }
    }
}

extern "C" void kernel_launch(void* const* d_in, const int* in_sizes, int n_in,
                              void* d_out, int out_size, void* d_ws, size_t ws_size,
                              hipStream_t stream) {
    const float* feat     = (const float*)d_in[0];
    const float* rois     = (const float*)d_in[1];
    const int*   img_size = (const int*)d_in[2];
    float* out = (float*)d_out;

    int n_rois = in_sizes[1] / 4;            // 512
    int grid   = n_rois * NSL;               // 4096 blocks

    roi_crop_resize_kernel<<<grid, 512, 0, stream>>>(feat, rois, img_size, out);
}